// Round 18
// baseline (1386.843 us; speedup 1.0000x reference)
//
#include <hip/hip_runtime.h>
#include <hip/hip_bf16.h>

// Problem constants (fixed by setup_inputs)
#define BB   16      // batches (N_t)
#define NQb  1560    // q rows per batch
#define CC   1024    // channels
#define HH   16      // heads
#define DD   64      // head dim
#define NAk  256     // keys per batch
#define CE   768     // encoder channels
#define MTOT (BB*NQb) // 24960
#define NTIL ((NQb + 31) / 32)  // 49 q-tiles of 32 rows
#define NB_Q 1560    // qproj tiles (195 x 8)
#define NB_KV 512    // kvproj tiles (32 x 16)

// 0.125 (D^-0.5) * log2(e): folded into Q-LN so softmax is exp2(s) directly.
// |s| <= 64*0.1803 = 11.54 (Cauchy-Schwarz on unit-variance LN outputs).
#define QSCALE 0.18033688011112042f

typedef __attribute__((ext_vector_type(8))) short bf16x8;
typedef __attribute__((ext_vector_type(4))) float f32x4;
typedef unsigned short u16;
typedef unsigned int u32;

__device__ __forceinline__ u16 f2bf(float f) {  // RNE fp32->bf16
  unsigned u = __builtin_bit_cast(unsigned, f);
  u += 0x7FFFu + ((u >> 16) & 1u);
  return (u16)(u >> 16);
}

__device__ __forceinline__ u32 cvtpk(float a, float b) {  // 2xf32 -> packed bf16
  u32 r;
  asm("v_cvt_pk_bf16_f32 %0, %1, %2" : "=v"(r) : "v"(a), "v"(b));
  return r;
}

__device__ __forceinline__ void gl2lds16(const void* g, void* l) {
  __builtin_amdgcn_global_load_lds(
      (const __attribute__((address_space(1))) void*)g,
      (__attribute__((address_space(3))) void*)l, 16, 0, 0);
}

__device__ __forceinline__ f32x4 mfma16(bf16x8 a, bf16x8 b, f32x4 c) {
  return __builtin_amdgcn_mfma_f32_16x16x32_bf16(a, b, c, 0, 0, 0);
}

// ---------------------------------------------------------------------------
// Fused fp32 -> bf16 convert for ALL five inputs in ONE launch (segment table).
// (Plain loads — NT loads measured -3us in R17.)
// ---------------------------------------------------------------------------
__global__ __launch_bounds__(256) void conv_all(
    const float* __restrict__ s0, const float* __restrict__ s1,
    const float* __restrict__ s2, const float* __restrict__ s3,
    const float* __restrict__ s4, u16* __restrict__ d0, u16* __restrict__ d1,
    u16* __restrict__ d2, u16* __restrict__ d3, u16* __restrict__ d4, int e0,
    int e1, int e2, int e3, int e4) {
  for (int i = blockIdx.x * 256 + threadIdx.x; i < e4; i += gridDim.x * 256) {
    const float* s; u16* d; int j;
    if (i < e0)      { s = s0; d = d0; j = i; }
    else if (i < e1) { s = s1; d = d1; j = i - e0; }
    else if (i < e2) { s = s2; d = d2; j = i - e1; }
    else if (i < e3) { s = s3; d = d3; j = i - e2; }
    else             { s = s4; d = d4; j = i - e3; }
    float4 v = reinterpret_cast<const float4*>(s)[j];
    ushort4 o;
    o.x = f2bf(v.x); o.y = f2bf(v.y); o.z = f2bf(v.z); o.w = f2bf(v.w);
    reinterpret_cast<ushort4*>(d)[j] = o;
  }
}

// ---------------------------------------------------------------------------
// m97-exact GEMM body (R14-proven best): out = A[M,KD]@W[N,KD]^T.
// 128x128 tile, BK=64, 4 waves (2x2, wave=64x64), 256 thr, SINGLE 32KB LDS
// buffer. Per K-tile: __syncthreads -> 8 gl2lds -> __syncthreads (compiler
// drains vmcnt) -> 16 ds_read_b128 + 32 MFMA (compiler fine-grained lgkm).
// Rows = 128B; XOR swizzle byte ^= (row&7)<<4 (conflict-free b128).
// EPI: 0 = per-head LN (eps 1e-6) * QSCALE -> bf16 o_bf [M,CC]
//      1 = KV: cols<CC LN (eps 1e-5) -> Kbf[b][h][na][d]; cols>=CC ->
//          Vt[b][h][d][na] (both bf16)
//      2 = bias -> fp32 o_f [M,CC] (nontemporal write-once output)
// ---------------------------------------------------------------------------
template <int KD, int EPI, int MROWS>
__device__ __forceinline__ void gemm_body(
    u16* LDS, int row0, int col0, const u16* __restrict__ A,
    const u16* __restrict__ W, const float* __restrict__ bias,
    const float* __restrict__ lnw, const float* __restrict__ lnb,
    u16* __restrict__ o_bf, u16* __restrict__ o_bf2,
    float* __restrict__ o_f) {
  constexpr int nt = KD / 64;
  const int tid = threadIdx.x;
  const int l = tid & 63, wid = tid >> 6;
  const int wr = wid >> 1, wc = wid & 1;  // 2x2 waves of 64x64
  const int g = l >> 4, ql = l & 15;

  // staging: 128 rows x 128B per matrix; thread: row sr (0..31, 4 issues),
  // 16B chunk c8; source pre-swizzled so linear LDS dest ends up swizzled.
  const int sr = tid >> 3, c8 = tid & 7;
  const int soff = ((c8 * 16) ^ ((sr & 7) << 4)) >> 1;  // elems
  char* lA = (char*)LDS + tid * 16;
  char* lB = (char*)LDS + 16384 + tid * 16;

  f32x4 acc[4][4];
#pragma unroll
  for (int m = 0; m < 4; ++m)
#pragma unroll
    for (int n = 0; n < 4; ++n) acc[m][n] = (f32x4){0.f, 0.f, 0.f, 0.f};

  for (int t = 0; t < nt; ++t) {
    const int k0 = t * 64;
    __syncthreads();  // all waves done reading previous tile
#pragma unroll
    for (int j = 0; j < 4; ++j) {
      int r = row0 + j * 32 + sr;
      r = min(r, MROWS - 1);
      gl2lds16(A + (size_t)r * KD + k0 + soff, lA + j * 4096);
    }
#pragma unroll
    for (int j = 0; j < 4; ++j)
      gl2lds16(W + (size_t)(col0 + j * 32 + sr) * KD + k0 + soff,
               lB + j * 4096);
    __syncthreads();  // compiler drains vmcnt(0) => staged data visible

    bf16x8 af[4][2], bfv[4][2];
#pragma unroll
    for (int m = 0; m < 4; ++m) {
      int ra = wr * 64 + m * 16 + ql;
      int rx = (ra & 7) << 4;
      const char* As = (const char*)LDS + ra * 128;
      af[m][0] = *(const bf16x8*)(As + ((g * 16) ^ rx));
      af[m][1] = *(const bf16x8*)(As + ((g * 16 + 64) ^ rx));
    }
#pragma unroll
    for (int n = 0; n < 4; ++n) {
      int rb = wc * 64 + n * 16 + ql;
      int rx = (rb & 7) << 4;
      const char* Bs = (const char*)LDS + 16384 + rb * 128;
      bfv[n][0] = *(const bf16x8*)(Bs + ((g * 16) ^ rx));
      bfv[n][1] = *(const bf16x8*)(Bs + ((g * 16 + 64) ^ rx));
    }
    __builtin_amdgcn_s_setprio(1);
#pragma unroll
    for (int kk = 0; kk < 2; ++kk)
#pragma unroll
      for (int m = 0; m < 4; ++m)
#pragma unroll
        for (int n = 0; n < 4; ++n)
          acc[m][n] = mfma16(af[m][kk], bfv[n][kk], acc[m][n]);
    __builtin_amdgcn_s_setprio(0);
  }

  // ---------------- epilogue ----------------
  const int colw = col0 + wc * 64;  // 64-aligned => exactly one head
  float bv[4];
#pragma unroll
  for (int n = 0; n < 4; ++n) bv[n] = bias[colw + n * 16 + ql];

  if constexpr (EPI == 2) {
#pragma unroll
    for (int m = 0; m < 4; ++m)
#pragma unroll
      for (int reg = 0; reg < 4; ++reg) {
        int grow = row0 + wr * 64 + m * 16 + g * 4 + reg;
        if (grow < MROWS) {
#pragma unroll
          for (int n = 0; n < 4; ++n)
            __builtin_nontemporal_store(
                acc[m][n][reg] + bv[n],
                &o_f[(size_t)grow * CC + colw + n * 16 + ql]);
        }
      }
    return;
  }

  if constexpr (EPI == 0) {
    float lwv[4], lbv[4];
#pragma unroll
    for (int n = 0; n < 4; ++n) {
      lwv[n] = lnw[n * 16 + ql] * QSCALE;
      lbv[n] = lnb[n * 16 + ql] * QSCALE;
    }
    const int head = colw >> 6;
#pragma unroll
    for (int m = 0; m < 4; ++m)
#pragma unroll
      for (int reg = 0; reg < 4; ++reg) {
        int grow = row0 + wr * 64 + m * 16 + g * 4 + reg;
        if (grow < MROWS) {
          float tv[4], s = 0.f, ss = 0.f;
#pragma unroll
          for (int n = 0; n < 4; ++n) {
            tv[n] = acc[m][n][reg] + bv[n];
            s += tv[n]; ss += tv[n] * tv[n];
          }
#pragma unroll
          for (int off = 1; off < 16; off <<= 1) {
            s  += __shfl_xor(s, off, 16);
            ss += __shfl_xor(ss, off, 16);
          }
          float mean = s * (1.f / 64.f);
          float var  = ss * (1.f / 64.f) - mean * mean;
          float rs_  = rsqrtf(var + 1e-6f);
          u16* dst = o_bf + (size_t)grow * CC + head * 64;
#pragma unroll
          for (int n = 0; n < 4; ++n)
            dst[n * 16 + ql] = f2bf((tv[n] - mean) * rs_ * lwv[n] + lbv[n]);
        }
      }
    return;
  }

  if constexpr (EPI == 1) {
    const bool isK = (colw < CC);
    const int head = (isK ? colw : (colw - CC)) >> 6;
    if (isK) {
      float lwv[4], lbv[4];
#pragma unroll
      for (int n = 0; n < 4; ++n) {
        lwv[n] = lnw[n * 16 + ql];
        lbv[n] = lnb[n * 16 + ql];
      }
#pragma unroll
      for (int m = 0; m < 4; ++m)
#pragma unroll
        for (int reg = 0; reg < 4; ++reg) {
          float tv[4], s = 0.f, ss = 0.f;
#pragma unroll
          for (int n = 0; n < 4; ++n) {
            tv[n] = acc[m][n][reg] + bv[n];
            s += tv[n]; ss += tv[n] * tv[n];
          }
#pragma unroll
          for (int off = 1; off < 16; off <<= 1) {
            s  += __shfl_xor(s, off, 16);
            ss += __shfl_xor(ss, off, 16);
          }
          float mean = s * (1.f / 64.f);
          float var  = ss * (1.f / 64.f) - mean * mean;
          float rs_  = rsqrtf(var + 1e-5f);
          int grow = row0 + wr * 64 + m * 16 + g * 4 + reg;
          int bb = grow >> 8, na = grow & 255;
          u16* dst = o_bf + (size_t)((bb * HH + head) * NAk + na) * DD;
#pragma unroll
          for (int n = 0; n < 4; ++n)
            dst[n * 16 + ql] = f2bf((tv[n] - mean) * rs_ * lwv[n] + lbv[n]);
        }
    } else {
#pragma unroll
      for (int m = 0; m < 4; ++m)
#pragma unroll
        for (int reg = 0; reg < 4; ++reg) {
          int grow = row0 + wr * 64 + m * 16 + g * 4 + reg;
          int bb = grow >> 8, na = grow & 255;
          u16* dst = o_bf2 + (size_t)(bb * HH + head) * DD * NAk + na;
#pragma unroll
          for (int n = 0; n < 4; ++n) {
            int d = n * 16 + ql;
            dst[(size_t)d * NAk] = f2bf(acc[m][n][reg] + bv[n]);
          }
        }
    }
    return;
  }
}

// ---------------------------------------------------------------------------
// Merged Q-proj + KV-proj: flat grid of 2072 blocks (1560 qproj + 512 kv),
// bijective XCD swizzle on the flat id (2072 % 8 == 0), block-uniform branch.
// __launch_bounds__(256,5): LDS 32KB allows 5 blocks/CU; VGPR cap 102
// (current use 80) — raise resident-block TLP to cover the stage drains.
// ---------------------------------------------------------------------------
__global__ __launch_bounds__(256, 5) void qkv_gemm(
    const u16* __restrict__ Xbf, const u16* __restrict__ QWb,
    const float* __restrict__ q_b, const float* __restrict__ qn_w,
    const float* __restrict__ qn_b, u16* __restrict__ Qbf,
    const u16* __restrict__ Ebf, const u16* __restrict__ KVWb,
    const float* __restrict__ kv_b, const float* __restrict__ kn_w,
    const float* __restrict__ kn_b, u16* __restrict__ Kbf,
    u16* __restrict__ Vtbf) {
  __shared__ u16 LDS[16384];  // 32KB single buffer
  const int bid = (int)blockIdx.x;
  constexpr int q8 = (NB_Q + NB_KV) / 8;  // 259
  const int nid = (bid & 7) * q8 + (bid >> 3);
  if (nid < NB_Q) {
    gemm_body<CC, 0, MTOT>(LDS, (nid / 8) * 128, (nid % 8) * 128, Xbf, QWb,
                           q_b, qn_w, qn_b, Qbf, nullptr, nullptr);
  } else {
    const int j = nid - NB_Q;
    gemm_body<CE, 1, BB * NAk>(LDS, (j / 16) * 128, (j % 16) * 128, Ebf, KVWb,
                               kv_b, kn_w, kn_b, Kbf, Vtbf, nullptr);
  }
}

// ---------------------------------------------------------------------------
// Standalone GEMM kernel (proj): same body, own XCD swizzle, same occupancy.
// ---------------------------------------------------------------------------
template <int KD, int EPI, int NXT, int MROWS>
__global__ __launch_bounds__(256, 5) void gemm_bf16(
    const u16* __restrict__ A, const u16* __restrict__ W,
    const float* __restrict__ bias, const float* __restrict__ lnw,
    const float* __restrict__ lnb, u16* __restrict__ o_bf,
    u16* __restrict__ o_bf2, float* __restrict__ o_f) {
  __shared__ u16 LDS[16384];  // 32KB single buffer
  const int orig = (int)blockIdx.x + NXT * (int)blockIdx.y;
  const int q8 = (NXT * (int)gridDim.y) >> 3;
  const int nid = (orig & 7) * q8 + (orig >> 3);
  gemm_body<KD, EPI, MROWS>(LDS, (nid / NXT) * 128, (nid % NXT) * 128, A, W,
                            bias, lnw, lnb, o_bf, o_bf2, o_f);
}

// ---------------------------------------------------------------------------
// MFMA attention (unchanged, known good): PERSISTENT per-(b,h) block.
// grid=(HH,BB), 768 threads = 12 waves. K + Vt staged once into swizzled
// LDS, waves sweep 32-row q-tiles; swapped QK^T, NO-MAX softmax, cvt_pk P
// pack, deferred 1/l.
// ---------------------------------------------------------------------------
__global__ __launch_bounds__(768) void attn_mfma(
    const u16* __restrict__ Qbf, const u16* __restrict__ Kbf,
    const u16* __restrict__ Vtbf, u16* __restrict__ Obf) {
  __shared__ u16 Ks[256 * 64];    // 32KB [key][d], row-XOR swizzled
  __shared__ u16 Vts[64 * 256];   // 32KB [d][key], row-XOR swizzled
  __shared__ u16 P[12][32][64];   // 48KB per-wave [32 q][64 keys]
  const int tid = threadIdx.x, l = tid & 63, wid = tid >> 6;
  const int g = l >> 4, ql = l & 15;
  const int h = blockIdx.x, b = blockIdx.y;
  const size_t kvbase = (size_t)(b * HH + h) * (NAk * DD);
  const u16* Kp = Kbf + kvbase;
  const u16* Vp = Vtbf + kvbase;
  char* Pw = (char*)&P[wid][0][0];
  const int swz = (ql & 7) << 4;

  for (int idx = tid; idx < 4096; idx += 768) {
    if (idx < 2048) {
      int kr = idx >> 3, kc = idx & 7;
      gl2lds16(Kp + kr * 64 + (((kc * 16) ^ ((kr & 7) << 4)) >> 1),
               (char*)Ks + idx * 16);
    } else {
      int j = idx - 2048;
      int vr = j >> 5, vc = j & 31;
      gl2lds16(Vp + vr * 256 + (((vc * 16) ^ ((vr & 7) << 4)) >> 1),
               (char*)Vts + j * 16);
    }
  }
  __syncthreads();

  const u16* Qb0 = Qbf + (size_t)b * NQb * CC + h * DD;
  u16* Ob0 = Obf + (size_t)b * NQb * CC + h * DD;

  for (int t = wid; t < NTIL; t += 12) {
    const int qr0 = t * 32;
    bf16x8 qf[2][2];
#pragma unroll
    for (int m = 0; m < 2; ++m) {
      int qrow = min(qr0 + m * 16 + ql, NQb - 1);
      const u16* p = Qb0 + (size_t)qrow * CC + g * 8;
      qf[m][0] = *(const bf16x8*)(p);
      qf[m][1] = *(const bf16x8*)(p + 32);
    }

    f32x4 oacc[2][4];
#pragma unroll
    for (int m = 0; m < 2; ++m)
#pragma unroll
      for (int n = 0; n < 4; ++n) oacc[m][n] = (f32x4){0.f, 0.f, 0.f, 0.f};
    float lsum[2] = {0.f, 0.f};

#pragma unroll
    for (int c = 0; c < 4; ++c) {
      f32x4 sf[2][4];
#pragma unroll
      for (int m = 0; m < 2; ++m)
#pragma unroll
        for (int n = 0; n < 4; ++n) sf[m][n] = (f32x4){0.f, 0.f, 0.f, 0.f};
      __builtin_amdgcn_s_setprio(1);
#pragma unroll
      for (int n = 0; n < 4; ++n) {
        const char* kbase = (const char*)Ks + (c * 64 + n * 16 + ql) * 128;
        bf16x8 ka0 = *(const bf16x8*)(kbase + ((g * 16) ^ swz));
        bf16x8 ka1 = *(const bf16x8*)(kbase + ((g * 16 + 64) ^ swz));
        sf[0][n] = mfma16(ka0, qf[0][0], sf[0][n]);
        sf[0][n] = mfma16(ka1, qf[0][1], sf[0][n]);
        sf[1][n] = mfma16(ka0, qf[1][0], sf[1][n]);
        sf[1][n] = mfma16(ka1, qf[1][1], sf[1][n]);
      }
      __builtin_amdgcn_s_setprio(0);

#pragma unroll
      for (int m = 0; m < 2; ++m) {
        float cs = 0.f;
#pragma unroll
        for (int n = 0; n < 4; ++n)
#pragma unroll
          for (int reg = 0; reg < 4; ++reg) {
            float e = exp2f(sf[m][n][reg]);
            sf[m][n][reg] = e;
            cs += e;
          }
        lsum[m] += cs;
        char* rowp = Pw + (m * 16 + ql) * 128;
#pragma unroll
        for (int n = 0; n < 4; ++n) {
          u32 w0 = cvtpk(sf[m][n][0], sf[m][n][1]);
          u32 w1 = cvtpk(sf[m][n][2], sf[m][n][3]);
          *(uint2*)(rowp + ((n * 32 + g * 8) ^ swz)) = make_uint2(w0, w1);
        }
      }

      __builtin_amdgcn_s_setprio(1);
#pragma unroll
      for (int ks = 0; ks < 2; ++ks) {
        bf16x8 pa[2], vb[4];
#pragma unroll
        for (int m = 0; m < 2; ++m)
          pa[m] = *(const bf16x8*)(Pw + (m * 16 + ql) * 128 +
                                   ((ks * 64 + g * 16) ^ swz));
#pragma unroll
        for (int n = 0; n < 4; ++n)
          vb[n] = *(const bf16x8*)((const char*)Vts + (n * 16 + ql) * 512 +
                                   ((c * 128 + ks * 64 + g * 16) ^ swz));
#pragma unroll
        for (int m = 0; m < 2; ++m)
#pragma unroll
          for (int n = 0; n < 4; ++n)
            oacc[m][n] = mfma16(pa[m], vb[n], oacc[m][n]);
      }
      __builtin_amdgcn_s_setprio(0);
    }

#pragma unroll
    for (int m = 0; m < 2; ++m) {
      lsum[m] += __shfl_xor(lsum[m], 16);
      lsum[m] += __shfl_xor(lsum[m], 32);
      float inv[4];
#pragma unroll
      for (int reg = 0; reg < 4; ++reg)
        inv[reg] = 1.f / __shfl(lsum[m], g * 4 + reg);
#pragma unroll
      for (int reg = 0; reg < 4; ++reg) {
        int qrow = qr0 + m * 16 + g * 4 + reg;
        if (qrow < NQb) {
          u16* dst = Ob0 + (size_t)qrow * CC;
#pragma unroll
          for (int n = 0; n < 4; ++n)
            dst[n * 16 + ql] = f2bf(oacc[m][n][reg] * inv[reg]);
        }
      }
    }
  }
}

// ---------------------------------------------------------------------------
extern "C" void kernel_launch(void* const* d_in, const int* in_sizes, int n_in,
                              void* d_out, int out_size, void* d_ws,
                              size_t ws_size, hipStream_t stream) {
  const float* x      = (const float*)d_in[0];
  const float* enc    = (const float*)d_in[1];
  const float* q_w    = (const float*)d_in[2];
  const float* q_b    = (const float*)d_in[3];
  const float* kv_w   = (const float*)d_in[4];
  const float* kv_b   = (const float*)d_in[5];
  const float* proj_w = (const float*)d_in[6];
  const float* proj_b = (const float*)d_in[7];
  const float* qn_w   = (const float*)d_in[8];
  const float* qn_b   = (const float*)d_in[9];
  const float* kn_w   = (const float*)d_in[10];
  const float* kn_b   = (const float*)d_in[11];
  float* out = (float*)d_out;

  u16* ws = (u16*)d_ws;
  size_t off = 0;
  u16* Xbf  = ws + off; off += (size_t)MTOT * CC;   // also reused as O
  u16* Qbf  = ws + off; off += (size_t)MTOT * CC;
  u16* Ebf  = ws + off; off += (size_t)BB * NAk * CE;
  u16* QWb  = ws + off; off += (size_t)CC * CC;
  u16* KVWb = ws + off; off += (size_t)2 * CC * CE;
  u16* PWb  = ws + off; off += (size_t)CC * CC;
  u16* Kbf  = ws + off; off += (size_t)BB * HH * NAk * DD;
  u16* Vtbf = ws + off; off += (size_t)BB * HH * NAk * DD;

  // single fused conversion launch (segments in float4 units)
  const int nx  = (MTOT * CC) / 4;
  const int ne  = (BB * NAk * CE) / 4;
  const int nqw = (CC * CC) / 4;
  const int nkv = (2 * CC * CE) / 4;
  const int npw = (CC * CC) / 4;
  conv_all<<<2048, 256, 0, stream>>>(
      x, enc, q_w, kv_w, proj_w, Xbf, Ebf, QWb, KVWb, PWb, nx, nx + ne,
      nx + ne + nqw, nx + ne + nqw + nkv, nx + ne + nqw + nkv + npw);

  // merged Q-proj + KV-proj (2072 blocks, flat grid)
  qkv_gemm<<<NB_Q + NB_KV, 256, 0, stream>>>(Xbf, QWb, q_b, qn_w, qn_b, Qbf,
                                             Ebf, KVWb, kv_b, kn_w, kn_b,
                                             Kbf, Vtbf);
  attn_mfma<<<dim3(HH, BB), 768, 0, stream>>>(Qbf, Kbf, Vtbf, Xbf);
  gemm_bf16<CC, 2, 8, MTOT><<<dim3(8, 195), 256, 0, stream>>>(
      Xbf, PWb, proj_b, nullptr, nullptr, nullptr, nullptr, out);
}

// Round 19
// 243.899 us; speedup vs baseline: 5.6861x; 5.6861x over previous
//
#include <hip/hip_runtime.h>
#include <hip/hip_bf16.h>

// Problem constants (fixed by setup_inputs)
#define BB   16      // batches (N_t)
#define NQb  1560    // q rows per batch
#define CC   1024    // channels
#define HH   16      // heads
#define DD   64      // head dim
#define NAk  256     // keys per batch
#define CE   768     // encoder channels
#define MTOT (BB*NQb) // 24960
#define NTIL ((NQb + 31) / 32)  // 49 q-tiles of 32 rows
#define NB_Q 1560    // qproj tiles (195 x 8)
#define NB_KV 512    // kvproj tiles (32 x 16)

// 0.125 (D^-0.5) * log2(e): folded into Q-LN so softmax is exp2(s) directly.
// |s| <= 64*0.1803 = 11.54 (Cauchy-Schwarz on unit-variance LN outputs).
#define QSCALE 0.18033688011112042f

typedef __attribute__((ext_vector_type(8))) short bf16x8;
typedef __attribute__((ext_vector_type(4))) float f32x4;
typedef unsigned short u16;
typedef unsigned int u32;

__device__ __forceinline__ u16 f2bf(float f) {  // RNE fp32->bf16
  unsigned u = __builtin_bit_cast(unsigned, f);
  u += 0x7FFFu + ((u >> 16) & 1u);
  return (u16)(u >> 16);
}

__device__ __forceinline__ u32 cvtpk(float a, float b) {  // 2xf32 -> packed bf16
  u32 r;
  asm("v_cvt_pk_bf16_f32 %0, %1, %2" : "=v"(r) : "v"(a), "v"(b));
  return r;
}

__device__ __forceinline__ void gl2lds16(const void* g, void* l) {
  __builtin_amdgcn_global_load_lds(
      (const __attribute__((address_space(1))) void*)g,
      (__attribute__((address_space(3))) void*)l, 16, 0, 0);
}

__device__ __forceinline__ f32x4 mfma16(bf16x8 a, bf16x8 b, f32x4 c) {
  return __builtin_amdgcn_mfma_f32_16x16x32_bf16(a, b, c, 0, 0, 0);
}

// ---------------------------------------------------------------------------
// Fused fp32 -> bf16 convert for ALL five inputs in ONE launch (segment table).
// ---------------------------------------------------------------------------
__global__ __launch_bounds__(256) void conv_all(
    const float* __restrict__ s0, const float* __restrict__ s1,
    const float* __restrict__ s2, const float* __restrict__ s3,
    const float* __restrict__ s4, u16* __restrict__ d0, u16* __restrict__ d1,
    u16* __restrict__ d2, u16* __restrict__ d3, u16* __restrict__ d4, int e0,
    int e1, int e2, int e3, int e4) {
  for (int i = blockIdx.x * 256 + threadIdx.x; i < e4; i += gridDim.x * 256) {
    const float* s; u16* d; int j;
    if (i < e0)      { s = s0; d = d0; j = i; }
    else if (i < e1) { s = s1; d = d1; j = i - e0; }
    else if (i < e2) { s = s2; d = d2; j = i - e1; }
    else if (i < e3) { s = s3; d = d3; j = i - e2; }
    else             { s = s4; d = d4; j = i - e3; }
    float4 v = reinterpret_cast<const float4*>(s)[j];
    ushort4 o;
    o.x = f2bf(v.x); o.y = f2bf(v.y); o.z = f2bf(v.z); o.w = f2bf(v.w);
    reinterpret_cast<ushort4*>(d)[j] = o;
  }
}

// ---------------------------------------------------------------------------
// m97-exact GEMM body (R14-proven best): out = A[M,KD]@W[N,KD]^T.
// 128x128 tile, BK=64, 4 waves (2x2, wave=64x64), 256 thr, SINGLE 32KB LDS
// buffer. Per K-tile: __syncthreads -> 8 gl2lds -> __syncthreads (compiler
// drains vmcnt) -> 16 ds_read_b128 + 32 MFMA (compiler fine-grained lgkm).
// Rows = 128B; XOR swizzle byte ^= (row&7)<<4 (conflict-free b128).
// Occupancy: __launch_bounds__(256,3) — (256,5) measured 922us (VGPR 48,
// acc spilled to scratch, 3.5GB spill traffic — R18). 3 blocks/CU is the
// sweet spot; do not raise.
// EPI: 0 = per-head LN (eps 1e-6) * QSCALE -> bf16 o_bf [M,CC]
//      1 = KV: cols<CC LN (eps 1e-5) -> Kbf[b][h][na][d]; cols>=CC ->
//          Vt[b][h][d][na] (both bf16)
//      2 = bias -> fp32 o_f [M,CC] (nontemporal write-once output)
// ---------------------------------------------------------------------------
template <int KD, int EPI, int MROWS>
__device__ __forceinline__ void gemm_body(
    u16* LDS, int row0, int col0, const u16* __restrict__ A,
    const u16* __restrict__ W, const float* __restrict__ bias,
    const float* __restrict__ lnw, const float* __restrict__ lnb,
    u16* __restrict__ o_bf, u16* __restrict__ o_bf2,
    float* __restrict__ o_f) {
  constexpr int nt = KD / 64;
  const int tid = threadIdx.x;
  const int l = tid & 63, wid = tid >> 6;
  const int wr = wid >> 1, wc = wid & 1;  // 2x2 waves of 64x64
  const int g = l >> 4, ql = l & 15;

  // staging: 128 rows x 128B per matrix; thread: row sr (0..31, 4 issues),
  // 16B chunk c8; source pre-swizzled so linear LDS dest ends up swizzled.
  const int sr = tid >> 3, c8 = tid & 7;
  const int soff = ((c8 * 16) ^ ((sr & 7) << 4)) >> 1;  // elems
  char* lA = (char*)LDS + tid * 16;
  char* lB = (char*)LDS + 16384 + tid * 16;

  f32x4 acc[4][4];
#pragma unroll
  for (int m = 0; m < 4; ++m)
#pragma unroll
    for (int n = 0; n < 4; ++n) acc[m][n] = (f32x4){0.f, 0.f, 0.f, 0.f};

  for (int t = 0; t < nt; ++t) {
    const int k0 = t * 64;
    __syncthreads();  // all waves done reading previous tile
#pragma unroll
    for (int j = 0; j < 4; ++j) {
      int r = row0 + j * 32 + sr;
      r = min(r, MROWS - 1);
      gl2lds16(A + (size_t)r * KD + k0 + soff, lA + j * 4096);
    }
#pragma unroll
    for (int j = 0; j < 4; ++j)
      gl2lds16(W + (size_t)(col0 + j * 32 + sr) * KD + k0 + soff,
               lB + j * 4096);
    __syncthreads();  // compiler drains vmcnt(0) => staged data visible

    bf16x8 af[4][2], bfv[4][2];
#pragma unroll
    for (int m = 0; m < 4; ++m) {
      int ra = wr * 64 + m * 16 + ql;
      int rx = (ra & 7) << 4;
      const char* As = (const char*)LDS + ra * 128;
      af[m][0] = *(const bf16x8*)(As + ((g * 16) ^ rx));
      af[m][1] = *(const bf16x8*)(As + ((g * 16 + 64) ^ rx));
    }
#pragma unroll
    for (int n = 0; n < 4; ++n) {
      int rb = wc * 64 + n * 16 + ql;
      int rx = (rb & 7) << 4;
      const char* Bs = (const char*)LDS + 16384 + rb * 128;
      bfv[n][0] = *(const bf16x8*)(Bs + ((g * 16) ^ rx));
      bfv[n][1] = *(const bf16x8*)(Bs + ((g * 16 + 64) ^ rx));
    }
    __builtin_amdgcn_s_setprio(1);
#pragma unroll
    for (int kk = 0; kk < 2; ++kk)
#pragma unroll
      for (int m = 0; m < 4; ++m)
#pragma unroll
        for (int n = 0; n < 4; ++n)
          acc[m][n] = mfma16(af[m][kk], bfv[n][kk], acc[m][n]);
    __builtin_amdgcn_s_setprio(0);
  }

  // ---------------- epilogue ----------------
  const int colw = col0 + wc * 64;  // 64-aligned => exactly one head
  float bv[4];
#pragma unroll
  for (int n = 0; n < 4; ++n) bv[n] = bias[colw + n * 16 + ql];

  if constexpr (EPI == 2) {
#pragma unroll
    for (int m = 0; m < 4; ++m)
#pragma unroll
      for (int reg = 0; reg < 4; ++reg) {
        int grow = row0 + wr * 64 + m * 16 + g * 4 + reg;
        if (grow < MROWS) {
#pragma unroll
          for (int n = 0; n < 4; ++n)
            __builtin_nontemporal_store(
                acc[m][n][reg] + bv[n],
                &o_f[(size_t)grow * CC + colw + n * 16 + ql]);
        }
      }
    return;
  }

  if constexpr (EPI == 0) {
    float lwv[4], lbv[4];
#pragma unroll
    for (int n = 0; n < 4; ++n) {
      lwv[n] = lnw[n * 16 + ql] * QSCALE;
      lbv[n] = lnb[n * 16 + ql] * QSCALE;
    }
    const int head = colw >> 6;
#pragma unroll
    for (int m = 0; m < 4; ++m)
#pragma unroll
      for (int reg = 0; reg < 4; ++reg) {
        int grow = row0 + wr * 64 + m * 16 + g * 4 + reg;
        if (grow < MROWS) {
          float tv[4], s = 0.f, ss = 0.f;
#pragma unroll
          for (int n = 0; n < 4; ++n) {
            tv[n] = acc[m][n][reg] + bv[n];
            s += tv[n]; ss += tv[n] * tv[n];
          }
#pragma unroll
          for (int off = 1; off < 16; off <<= 1) {
            s  += __shfl_xor(s, off, 16);
            ss += __shfl_xor(ss, off, 16);
          }
          float mean = s * (1.f / 64.f);
          float var  = ss * (1.f / 64.f) - mean * mean;
          float rs_  = rsqrtf(var + 1e-6f);
          u16* dst = o_bf + (size_t)grow * CC + head * 64;
#pragma unroll
          for (int n = 0; n < 4; ++n)
            dst[n * 16 + ql] = f2bf((tv[n] - mean) * rs_ * lwv[n] + lbv[n]);
        }
      }
    return;
  }

  if constexpr (EPI == 1) {
    const bool isK = (colw < CC);
    const int head = (isK ? colw : (colw - CC)) >> 6;
    if (isK) {
      float lwv[4], lbv[4];
#pragma unroll
      for (int n = 0; n < 4; ++n) {
        lwv[n] = lnw[n * 16 + ql];
        lbv[n] = lnb[n * 16 + ql];
      }
#pragma unroll
      for (int m = 0; m < 4; ++m)
#pragma unroll
        for (int reg = 0; reg < 4; ++reg) {
          float tv[4], s = 0.f, ss = 0.f;
#pragma unroll
          for (int n = 0; n < 4; ++n) {
            tv[n] = acc[m][n][reg] + bv[n];
            s += tv[n]; ss += tv[n] * tv[n];
          }
#pragma unroll
          for (int off = 1; off < 16; off <<= 1) {
            s  += __shfl_xor(s, off, 16);
            ss += __shfl_xor(ss, off, 16);
          }
          float mean = s * (1.f / 64.f);
          float var  = ss * (1.f / 64.f) - mean * mean;
          float rs_  = rsqrtf(var + 1e-5f);
          int grow = row0 + wr * 64 + m * 16 + g * 4 + reg;
          int bb = grow >> 8, na = grow & 255;
          u16* dst = o_bf + (size_t)((bb * HH + head) * NAk + na) * DD;
#pragma unroll
          for (int n = 0; n < 4; ++n)
            dst[n * 16 + ql] = f2bf((tv[n] - mean) * rs_ * lwv[n] + lbv[n]);
        }
    } else {
#pragma unroll
      for (int m = 0; m < 4; ++m)
#pragma unroll
        for (int reg = 0; reg < 4; ++reg) {
          int grow = row0 + wr * 64 + m * 16 + g * 4 + reg;
          int bb = grow >> 8, na = grow & 255;
          u16* dst = o_bf2 + (size_t)(bb * HH + head) * DD * NAk + na;
#pragma unroll
          for (int n = 0; n < 4; ++n) {
            int d = n * 16 + ql;
            dst[(size_t)d * NAk] = f2bf(acc[m][n][reg] + bv[n]);
          }
        }
    }
    return;
  }
}

// ---------------------------------------------------------------------------
// Merged Q-proj + KV-proj: flat grid of 2072 blocks (1560 qproj + 512 kv),
// bijective XCD swizzle on the flat id (2072 % 8 == 0), block-uniform branch.
// ---------------------------------------------------------------------------
__global__ __launch_bounds__(256, 3) void qkv_gemm(
    const u16* __restrict__ Xbf, const u16* __restrict__ QWb,
    const float* __restrict__ q_b, const float* __restrict__ qn_w,
    const float* __restrict__ qn_b, u16* __restrict__ Qbf,
    const u16* __restrict__ Ebf, const u16* __restrict__ KVWb,
    const float* __restrict__ kv_b, const float* __restrict__ kn_w,
    const float* __restrict__ kn_b, u16* __restrict__ Kbf,
    u16* __restrict__ Vtbf) {
  __shared__ u16 LDS[16384];  // 32KB single buffer
  const int bid = (int)blockIdx.x;
  constexpr int q8 = (NB_Q + NB_KV) / 8;  // 259
  const int nid = (bid & 7) * q8 + (bid >> 3);
  if (nid < NB_Q) {
    gemm_body<CC, 0, MTOT>(LDS, (nid / 8) * 128, (nid % 8) * 128, Xbf, QWb,
                           q_b, qn_w, qn_b, Qbf, nullptr, nullptr);
  } else {
    const int j = nid - NB_Q;
    gemm_body<CE, 1, BB * NAk>(LDS, (j / 16) * 128, (j % 16) * 128, Ebf, KVWb,
                               kv_b, kn_w, kn_b, Kbf, Vtbf, nullptr);
  }
}

// ---------------------------------------------------------------------------
// Standalone GEMM kernel (proj): same body, own XCD swizzle.
// ---------------------------------------------------------------------------
template <int KD, int EPI, int NXT, int MROWS>
__global__ __launch_bounds__(256, 3) void gemm_bf16(
    const u16* __restrict__ A, const u16* __restrict__ W,
    const float* __restrict__ bias, const float* __restrict__ lnw,
    const float* __restrict__ lnb, u16* __restrict__ o_bf,
    u16* __restrict__ o_bf2, float* __restrict__ o_f) {
  __shared__ u16 LDS[16384];  // 32KB single buffer
  const int orig = (int)blockIdx.x + NXT * (int)blockIdx.y;
  const int q8 = (NXT * (int)gridDim.y) >> 3;
  const int nid = (orig & 7) * q8 + (orig >> 3);
  gemm_body<KD, EPI, MROWS>(LDS, (nid / NXT) * 128, (nid % NXT) * 128, A, W,
                            bias, lnw, lnb, o_bf, o_bf2, o_f);
}

// ---------------------------------------------------------------------------
// MFMA attention (unchanged, known good): PERSISTENT per-(b,h) block.
// grid=(HH,BB), 768 threads = 12 waves. K + Vt staged once into swizzled
// LDS, waves sweep 32-row q-tiles; swapped QK^T, NO-MAX softmax, cvt_pk P
// pack, deferred 1/l.
// ---------------------------------------------------------------------------
__global__ __launch_bounds__(768) void attn_mfma(
    const u16* __restrict__ Qbf, const u16* __restrict__ Kbf,
    const u16* __restrict__ Vtbf, u16* __restrict__ Obf) {
  __shared__ u16 Ks[256 * 64];    // 32KB [key][d], row-XOR swizzled
  __shared__ u16 Vts[64 * 256];   // 32KB [d][key], row-XOR swizzled
  __shared__ u16 P[12][32][64];   // 48KB per-wave [32 q][64 keys]
  const int tid = threadIdx.x, l = tid & 63, wid = tid >> 6;
  const int g = l >> 4, ql = l & 15;
  const int h = blockIdx.x, b = blockIdx.y;
  const size_t kvbase = (size_t)(b * HH + h) * (NAk * DD);
  const u16* Kp = Kbf + kvbase;
  const u16* Vp = Vtbf + kvbase;
  char* Pw = (char*)&P[wid][0][0];
  const int swz = (ql & 7) << 4;

  for (int idx = tid; idx < 4096; idx += 768) {
    if (idx < 2048) {
      int kr = idx >> 3, kc = idx & 7;
      gl2lds16(Kp + kr * 64 + (((kc * 16) ^ ((kr & 7) << 4)) >> 1),
               (char*)Ks + idx * 16);
    } else {
      int j = idx - 2048;
      int vr = j >> 5, vc = j & 31;
      gl2lds16(Vp + vr * 256 + (((vc * 16) ^ ((vr & 7) << 4)) >> 1),
               (char*)Vts + j * 16);
    }
  }
  __syncthreads();

  const u16* Qb0 = Qbf + (size_t)b * NQb * CC + h * DD;
  u16* Ob0 = Obf + (size_t)b * NQb * CC + h * DD;

  for (int t = wid; t < NTIL; t += 12) {
    const int qr0 = t * 32;
    bf16x8 qf[2][2];
#pragma unroll
    for (int m = 0; m < 2; ++m) {
      int qrow = min(qr0 + m * 16 + ql, NQb - 1);
      const u16* p = Qb0 + (size_t)qrow * CC + g * 8;
      qf[m][0] = *(const bf16x8*)(p);
      qf[m][1] = *(const bf16x8*)(p + 32);
    }

    f32x4 oacc[2][4];
#pragma unroll
    for (int m = 0; m < 2; ++m)
#pragma unroll
      for (int n = 0; n < 4; ++n) oacc[m][n] = (f32x4){0.f, 0.f, 0.f, 0.f};
    float lsum[2] = {0.f, 0.f};

#pragma unroll
    for (int c = 0; c < 4; ++c) {
      f32x4 sf[2][4];
#pragma unroll
      for (int m = 0; m < 2; ++m)
#pragma unroll
        for (int n = 0; n < 4; ++n) sf[m][n] = (f32x4){0.f, 0.f, 0.f, 0.f};
      __builtin_amdgcn_s_setprio(1);
#pragma unroll
      for (int n = 0; n < 4; ++n) {
        const char* kbase = (const char*)Ks + (c * 64 + n * 16 + ql) * 128;
        bf16x8 ka0 = *(const bf16x8*)(kbase + ((g * 16) ^ swz));
        bf16x8 ka1 = *(const bf16x8*)(kbase + ((g * 16 + 64) ^ swz));
        sf[0][n] = mfma16(ka0, qf[0][0], sf[0][n]);
        sf[0][n] = mfma16(ka1, qf[0][1], sf[0][n]);
        sf[1][n] = mfma16(ka0, qf[1][0], sf[1][n]);
        sf[1][n] = mfma16(ka1, qf[1][1], sf[1][n]);
      }
      __builtin_amdgcn_s_setprio(0);

#pragma unroll
      for (int m = 0; m < 2; ++m) {
        float cs = 0.f;
#pragma unroll
        for (int n = 0; n < 4; ++n)
#pragma unroll
          for (int reg = 0; reg < 4; ++reg) {
            float e = exp2f(sf[m][n][reg]);
            sf[m][n][reg] = e;
            cs += e;
          }
        lsum[m] += cs;
        char* rowp = Pw + (m * 16 + ql) * 128;
#pragma unroll
        for (int n = 0; n < 4; ++n) {
          u32 w0 = cvtpk(sf[m][n][0], sf[m][n][1]);
          u32 w1 = cvtpk(sf[m][n][2], sf[m][n][3]);
          *(uint2*)(rowp + ((n * 32 + g * 8) ^ swz)) = make_uint2(w0, w1);
        }
      }

      __builtin_amdgcn_s_setprio(1);
#pragma unroll
      for (int ks = 0; ks < 2; ++ks) {
        bf16x8 pa[2], vb[4];
#pragma unroll
        for (int m = 0; m < 2; ++m)
          pa[m] = *(const bf16x8*)(Pw + (m * 16 + ql) * 128 +
                                   ((ks * 64 + g * 16) ^ swz));
#pragma unroll
        for (int n = 0; n < 4; ++n)
          vb[n] = *(const bf16x8*)((const char*)Vts + (n * 16 + ql) * 512 +
                                   ((c * 128 + ks * 64 + g * 16) ^ swz));
#pragma unroll
        for (int m = 0; m < 2; ++m)
#pragma unroll
          for (int n = 0; n < 4; ++n)
            oacc[m][n] = mfma16(pa[m], vb[n], oacc[m][n]);
      }
      __builtin_amdgcn_s_setprio(0);
    }

#pragma unroll
    for (int m = 0; m < 2; ++m) {
      lsum[m] += __shfl_xor(lsum[m], 16);
      lsum[m] += __shfl_xor(lsum[m], 32);
      float inv[4];
#pragma unroll
      for (int reg = 0; reg < 4; ++reg)
        inv[reg] = 1.f / __shfl(lsum[m], g * 4 + reg);
#pragma unroll
      for (int reg = 0; reg < 4; ++reg) {
        int qrow = qr0 + m * 16 + g * 4 + reg;
        if (qrow < NQb) {
          u16* dst = Ob0 + (size_t)qrow * CC;
#pragma unroll
          for (int n = 0; n < 4; ++n)
            dst[n * 16 + ql] = f2bf(oacc[m][n][reg] * inv[reg]);
        }
      }
    }
  }
}

// ---------------------------------------------------------------------------
extern "C" void kernel_launch(void* const* d_in, const int* in_sizes, int n_in,
                              void* d_out, int out_size, void* d_ws,
                              size_t ws_size, hipStream_t stream) {
  const float* x      = (const float*)d_in[0];
  const float* enc    = (const float*)d_in[1];
  const float* q_w    = (const float*)d_in[2];
  const float* q_b    = (const float*)d_in[3];
  const float* kv_w   = (const float*)d_in[4];
  const float* kv_b   = (const float*)d_in[5];
  const float* proj_w = (const float*)d_in[6];
  const float* proj_b = (const float*)d_in[7];
  const float* qn_w   = (const float*)d_in[8];
  const float* qn_b   = (const float*)d_in[9];
  const float* kn_w   = (const float*)d_in[10];
  const float* kn_b   = (const float*)d_in[11];
  float* out = (float*)d_out;

  u16* ws = (u16*)d_ws;
  size_t off = 0;
  u16* Xbf  = ws + off; off += (size_t)MTOT * CC;   // also reused as O
  u16* Qbf  = ws + off; off += (size_t)MTOT * CC;
  u16* Ebf  = ws + off; off += (size_t)BB * NAk * CE;
  u16* QWb  = ws + off; off += (size_t)CC * CC;
  u16* KVWb = ws + off; off += (size_t)2 * CC * CE;
  u16* PWb  = ws + off; off += (size_t)CC * CC;
  u16* Kbf  = ws + off; off += (size_t)BB * HH * NAk * DD;
  u16* Vtbf = ws + off; off += (size_t)BB * HH * NAk * DD;

  // single fused conversion launch (segments in float4 units)
  const int nx  = (MTOT * CC) / 4;
  const int ne  = (BB * NAk * CE) / 4;
  const int nqw = (CC * CC) / 4;
  const int nkv = (2 * CC * CE) / 4;
  const int npw = (CC * CC) / 4;
  conv_all<<<2048, 256, 0, stream>>>(
      x, enc, q_w, kv_w, proj_w, Xbf, Ebf, QWb, KVWb, PWb, nx, nx + ne,
      nx + ne + nqw, nx + ne + nqw + nkv, nx + ne + nqw + nkv + npw);

  // merged Q-proj + KV-proj (2072 blocks, flat grid)
  qkv_gemm<<<NB_Q + NB_KV, 256, 0, stream>>>(Xbf, QWb, q_b, qn_w, qn_b, Qbf,
                                             Ebf, KVWb, kv_b, kn_w, kn_b,
                                             Kbf, Vtbf);
  attn_mfma<<<dim3(HH, BB), 768, 0, stream>>>(Qbf, Kbf, Vtbf, Xbf);
  gemm_bf16<CC, 2, 8, MTOT><<<dim3(8, 195), 256, 0, stream>>>(
      Xbf, PWb, proj_b, nullptr, nullptr, nullptr, nullptr, out);
}